// Round 3
// baseline (110.402 us; speedup 1.0000x reference)
//
#include <hip/hip_runtime.h>
#include <math.h>

// Problem constants (B, D, C) from the reference.
#define NB 4096
#define ND 3072
#define NC 10
#define NM 9   // C-1

static constexpr float kEps      = 0.1f;
static constexpr float kNumStab  = 1e-6f;
static constexpr float kAlpha    = 1.0f - (float)NC * kNumStab;  // 1 - C*num_stab
static constexpr float kInvSqrtC = 0.31622776601683794f;         // 1/sqrt(10)

// ---------------------------------------------------------------------------
// Kernel 1: gram_zero. ONE block, 1024 threads. Stages W (120 KB) into LDS
// with coalesced float4 loads, then each thread accumulates outer products of
// 3 W-rows into the 55 upper-triangular G entries, butterfly-reduces across
// the wave, combines 16 waves via LDS, writes G[10][10] to ws, and zeroes
// out[0] (d_out is re-poisoned to 0xAA before every timed replay).
// Replaces the former memset launch + 100-block scattered-load gram kernel.
// ---------------------------------------------------------------------------
__global__ __launch_bounds__(1024) void gram_zero_kernel(
        const float* __restrict__ W, float* __restrict__ G,
        float* __restrict__ out) {
    __shared__ float Wls[ND * NC];        // 122880 B, row-major copy of W
    __shared__ float part[16][56];        // per-wave partials (padded)

    const int tid  = threadIdx.x;
    const int lane = tid & 63;
    const int wv   = tid >> 6;

    // Coalesced stage W -> LDS.
    for (int i = tid; i < (ND * NC) / 4; i += 1024) {
        reinterpret_cast<float4*>(Wls)[i] = reinterpret_cast<const float4*>(W)[i];
    }
    __syncthreads();

    // Each thread: rows tid, tid+1024, tid+2048. 55 upper-tri accumulators.
    float a[55];
    #pragma unroll
    for (int c = 0; c < 55; ++c) a[c] = 0.0f;

    #pragma unroll
    for (int rr = 0; rr < 3; ++rr) {
        const int row = tid + rr * 1024;
        const float* rp = &Wls[row * NC];
        float r[NC];
        #pragma unroll
        for (int h = 0; h < 5; ++h) {
            const float2 v = *reinterpret_cast<const float2*>(rp + 2 * h);
            r[2 * h] = v.x; r[2 * h + 1] = v.y;
        }
        int c = 0;
        #pragma unroll
        for (int i = 0; i < NC; ++i)
            #pragma unroll
            for (int j = i; j < NC; ++j) {
                a[c] = fmaf(r[i], r[j], a[c]);
                ++c;
            }
    }

    // Butterfly-reduce all 55 across the wave.
    #pragma unroll
    for (int c = 0; c < 55; ++c) {
        #pragma unroll
        for (int off = 32; off > 0; off >>= 1) a[c] += __shfl_xor(a[c], off, 64);
    }
    if (lane == 0) {
        #pragma unroll
        for (int c = 0; c < 55; ++c) part[wv][c] = a[c];
    }
    __syncthreads();

    if (tid < 55) {
        float g = 0.0f;
        #pragma unroll
        for (int w = 0; w < 16; ++w) g += part[w][tid];
        // Decode upper-tri index tid -> (i, j), i <= j.
        int idx = tid, i = 0;
        while (idx >= (NC - i)) { idx -= (NC - i); ++i; }
        const int j = i + idx;
        G[i * NC + j] = g;
        G[j * NC + i] = g;
    }
    if (tid == 1023) out[0] = 0.0f;
}

// ---------------------------------------------------------------------------
// Kernel 2: main. Block = 512 threads = 8 waves, grid = 256 (1 block/CU).
// Whole W staged TRANSPOSED in LDS (Wt[k][d], 120 KB) -> inner loop reads W
// via conflict-free ds_read_b128. Each wave owns 2 samples over the FULL D
// range; after the in-wave butterfly, lanes 0/1 hold complete z[10] and run
// the analytic epilogue (Jacobian norm via the 10x10 Gram matrix — the [9,D]
// Jacobian is never materialized).
// Data prefetch is issued BEFORE the W-staging phase (covers staging latency)
// and runs 2 iterations deep (4 float4/wave in flight).
// ---------------------------------------------------------------------------
__global__ __launch_bounds__(512) void jacreg_kernel(
        const float* __restrict__ data, const float* __restrict__ W,
        const float* __restrict__ G, float* __restrict__ out) {
    __shared__ float Wts[NC * ND];   // 122880 B, k-major: Wts[k*ND + d]
    __shared__ float Gs[100];
    __shared__ float regs[16];

    const int tid  = threadIdx.x;
    const int lane = tid & 63;
    const int wv   = tid >> 6;

    const int s0 = blockIdx.x * 16 + wv * 2;     // this wave's 2 samples
    const float* __restrict__ r0 = data + (size_t)s0 * ND;
    const float* __restrict__ r1 = r0 + ND;

    // Issue the first two iterations' data loads BEFORE staging W so the
    // HBM stream starts immediately.
    float4 x0a = reinterpret_cast<const float4*>(r0)[lane];
    float4 x1a = reinterpret_cast<const float4*>(r1)[lane];
    float4 x0b = reinterpret_cast<const float4*>(r0)[64 + lane];
    float4 x1b = reinterpret_cast<const float4*>(r1)[64 + lane];

    if (tid < 100) Gs[tid] = G[tid];

    // Stage W -> LDS transposed. Coalesced float4 global reads; scattered
    // one-time LDS scalar writes (60 per thread).
    for (int i = tid; i < (ND * NC) / 4; i += 512) {
        const float4 w4 = reinterpret_cast<const float4*>(W)[i];
        const float* wp = reinterpret_cast<const float*>(&w4);
        const int e0 = i * 4;
        #pragma unroll
        for (int j = 0; j < 4; ++j) {
            const int e = e0 + j;
            Wts[(e % NC) * ND + (e / NC)] = wp[j];
        }
    }
    __syncthreads();

    float acc[2][NC];
    #pragma unroll
    for (int s = 0; s < 2; ++s)
        #pragma unroll
        for (int k = 0; k < NC; ++k) acc[s][k] = 0.0f;

    // 12 iterations of 256 d each (64 lanes x float4), 2-deep prefetch.
    for (int it = 0; it < 12; ++it) {
        const int pit = (it + 2 <= 11) ? it + 2 : 11;
        const float4 n0 = reinterpret_cast<const float4*>(r0)[pit * 64 + lane];
        const float4 n1 = reinterpret_cast<const float4*>(r1)[pit * 64 + lane];

        const int dbase = it * 256 + lane * 4;
        #pragma unroll
        for (int k = 0; k < NC; ++k) {
            const float4 wt = *reinterpret_cast<const float4*>(&Wts[k * ND + dbase]);
            acc[0][k] = fmaf(x0a.x, wt.x, acc[0][k]);
            acc[0][k] = fmaf(x0a.y, wt.y, acc[0][k]);
            acc[0][k] = fmaf(x0a.z, wt.z, acc[0][k]);
            acc[0][k] = fmaf(x0a.w, wt.w, acc[0][k]);
            acc[1][k] = fmaf(x1a.x, wt.x, acc[1][k]);
            acc[1][k] = fmaf(x1a.y, wt.y, acc[1][k]);
            acc[1][k] = fmaf(x1a.z, wt.z, acc[1][k]);
            acc[1][k] = fmaf(x1a.w, wt.w, acc[1][k]);
        }
        x0a = x0b; x1a = x1b;
        x0b = n0;  x1b = n1;
    }

    // In-wave butterfly: every lane ends with the full z for both samples.
    #pragma unroll
    for (int s = 0; s < 2; ++s)
        #pragma unroll
        for (int k = 0; k < NC; ++k) {
            float v = acc[s][k];
            #pragma unroll
            for (int off = 32; off > 0; off >>= 1) v += __shfl_xor(v, off, 64);
            acc[s][k] = v;
        }

    // Analytic epilogue: lane 0 -> sample s0, lane 1 -> sample s0+1.
    if (lane < 2) {
        float z[NC];
        #pragma unroll
        for (int k = 0; k < NC; ++k) z[k] = (lane == 0) ? acc[0][k] : acc[1][k];

        float zm = z[0];
        #pragma unroll
        for (int k = 1; k < NC; ++k) zm = fmaxf(zm, z[k]);
        float e[NC], Zs = 0.0f;
        #pragma unroll
        for (int k = 0; k < NC; ++k) { e[k] = expf(z[k] - zm); Zs += e[k]; }
        const float inv = 1.0f / Zs;

        float sg[NC], p[NC], sq[NC], u[NC];
        #pragma unroll
        for (int k = 0; k < NC; ++k) {
            sg[k] = e[k] * inv;                 // softmax probs (sigma)
            p[k]  = kAlpha * sg[k] + kNumStab;  // stabilized probs
            sq[k] = sqrtf(p[k]);                // s
            u[k]  = sg[k] / sq[k];              // sigma / s
        }
        const float q = 1.0f - sq[NM];

        // v = G*sigma, t = sigma^T G sigma
        float v[NC], t = 0.0f;
        #pragma unroll
        for (int k = 0; k < NC; ++k) {
            float a = 0.0f;
            #pragma unroll
            for (int j = 0; j < NC; ++j) a = fmaf(Gs[k * NC + j], sg[j], a);
            v[k] = a;
            t = fmaf(sg[k], a, t);
        }
        const float vM = v[NM], uM = u[NM];
        const float QMM = Gs[NC * NC - 1] - 2.0f * vM + t;

        float sumJ = 0.0f;
        #pragma unroll
        for (int i = 0; i < NM; ++i) {
            const float Qii = Gs[i * NC + i] - 2.0f * v[i] + t;
            const float QiM = Gs[i * NC + NM] - v[i] - vM + t;
            const float r = sq[i] / q;
            sumJ += u[i] * u[i] * Qii
                  + 2.0f * u[i] * uM * r * QiM
                  + uM * uM * r * r * QMM;
        }
        const float jn = (kAlpha / q) * sqrtf(fmaxf(sumJ, 0.0f));

        float ssum = 0.0f;
        #pragma unroll
        for (int k = 0; k < NC; ++k) ssum += sq[k];
        const float ac = fminf(1.0f, fmaxf(-1.0f, ssum * kInvSqrtC));
        const float delta = 2.0f * acosf(ac);

        float psum = 0.0f;
        #pragma unroll
        for (int k = 0; k < NM; ++k) psum += p[k];
        const float rho = (2.0f * q - psum) / q;

        const float a = jn - delta / (rho * kEps);
        regs[wv * 2 + lane] = (a > 0.0f) ? a : expm1f(a);
    }
    __syncthreads();
    if (tid == 0) {
        float bs = 0.0f;
        #pragma unroll
        for (int i = 0; i < 16; ++i) bs += regs[i];
        atomicAdd(out, bs * (1.0f / (float)NB));
    }
}

extern "C" void kernel_launch(void* const* d_in, const int* in_sizes, int n_in,
                              void* d_out, int out_size, void* d_ws, size_t ws_size,
                              hipStream_t stream) {
    const float* data = (const float*)d_in[0];
    const float* W    = (const float*)d_in[1];
    float* out = (float*)d_out;
    float* G   = (float*)d_ws;   // 100 floats of scratch for the Gram matrix

    // gram_zero also zeroes out[0] (re-poisoned to 0xAA before every replay),
    // so the separate memset launch is gone.
    gram_zero_kernel<<<1, 1024, 0, stream>>>(W, G, out);
    jacreg_kernel<<<NB / 16, 512, 0, stream>>>(data, W, G, out);
}

// Round 4
// 104.235 us; speedup vs baseline: 1.0592x; 1.0592x over previous
//
#include <hip/hip_runtime.h>
#include <math.h>

// Problem constants (B, D, C) from the reference.
#define NB 4096
#define ND 3072
#define NC 10
#define NM 9   // C-1

static constexpr float kEps      = 0.1f;
static constexpr float kNumStab  = 1e-6f;
static constexpr float kAlpha    = 1.0f - (float)NC * kNumStab;  // 1 - C*num_stab
static constexpr float kInvSqrtC = 0.31622776601683794f;         // 1/sqrt(10)

// ---------------------------------------------------------------------------
// Single fused kernel. Block = 512 threads = 8 waves, grid = 256 (1 block/CU,
// LDS-bound at ~125 KB).
//
// Phase 1: stage all of W TRANSPOSED into LDS (Wt[k][d], 120 KB) with
//          coalesced float4 global reads. First data prefetches are issued
//          BEFORE staging so the HBM stream starts immediately.
// Phase 2: HBM-bound main loop — each wave owns 2 samples over the full D
//          range, z += x*Wt via conflict-free ds_read_b128, 2-deep prefetch.
//          In-wave butterfly leaves complete z[10] in every lane.
// Phase 3: G = W^T W computed REDUNDANTLY per block from the LDS-resident Wt
//          (epilogue-only dependency -> off the HBM critical path; replaces
//          the serialized gram pre-kernel that regressed R3).
// Phase 4: analytic epilogue on lanes 0/1 of each wave: the [9,D] Jacobian is
//          never materialized — ||J||_F^2 collapses to a quadratic form in
//          the 10x10 Gram matrix. One atomicAdd per block.
// ---------------------------------------------------------------------------
__global__ __launch_bounds__(512) void jacreg_fused_kernel(
        const float* __restrict__ data, const float* __restrict__ W,
        float* __restrict__ out) {
    __shared__ float Wts[NC * ND];     // 122880 B, k-major: Wts[k*ND + d]
    __shared__ float gpart[8][56];     // per-wave G partials (padded)
    __shared__ float Gs[100];
    __shared__ float regs[16];

    const int tid  = threadIdx.x;
    const int lane = tid & 63;
    const int wv   = tid >> 6;

    const int s0 = blockIdx.x * 16 + wv * 2;     // this wave's 2 samples
    const float* __restrict__ r0 = data + (size_t)s0 * ND;
    const float* __restrict__ r1 = r0 + ND;

    // Issue the first two iterations' data loads BEFORE staging W.
    float4 x0a = reinterpret_cast<const float4*>(r0)[lane];
    float4 x1a = reinterpret_cast<const float4*>(r1)[lane];
    float4 x0b = reinterpret_cast<const float4*>(r0)[64 + lane];
    float4 x1b = reinterpret_cast<const float4*>(r1)[64 + lane];

    // Phase 1: stage W -> LDS transposed. Coalesced float4 global reads;
    // scattered one-time scalar LDS writes (60 per thread).
    for (int i = tid; i < (ND * NC) / 4; i += 512) {
        const float4 w4 = reinterpret_cast<const float4*>(W)[i];
        const float* wp = reinterpret_cast<const float*>(&w4);
        const int e0 = i * 4;
        #pragma unroll
        for (int j = 0; j < 4; ++j) {
            const int e = e0 + j;
            Wts[(e % NC) * ND + (e / NC)] = wp[j];
        }
    }
    __syncthreads();

    // Phase 2: main loop. 12 iterations of 256 d each (64 lanes x float4).
    float acc[2][NC];
    #pragma unroll
    for (int s = 0; s < 2; ++s)
        #pragma unroll
        for (int k = 0; k < NC; ++k) acc[s][k] = 0.0f;

    for (int it = 0; it < 12; ++it) {
        const int pit = (it + 2 <= 11) ? it + 2 : 11;
        const float4 n0 = reinterpret_cast<const float4*>(r0)[pit * 64 + lane];
        const float4 n1 = reinterpret_cast<const float4*>(r1)[pit * 64 + lane];

        const int dbase = it * 256 + lane * 4;
        #pragma unroll
        for (int k = 0; k < NC; ++k) {
            const float4 wt = *reinterpret_cast<const float4*>(&Wts[k * ND + dbase]);
            acc[0][k] = fmaf(x0a.x, wt.x, acc[0][k]);
            acc[0][k] = fmaf(x0a.y, wt.y, acc[0][k]);
            acc[0][k] = fmaf(x0a.z, wt.z, acc[0][k]);
            acc[0][k] = fmaf(x0a.w, wt.w, acc[0][k]);
            acc[1][k] = fmaf(x1a.x, wt.x, acc[1][k]);
            acc[1][k] = fmaf(x1a.y, wt.y, acc[1][k]);
            acc[1][k] = fmaf(x1a.z, wt.z, acc[1][k]);
            acc[1][k] = fmaf(x1a.w, wt.w, acc[1][k]);
        }
        x0a = x0b; x1a = x1b;
        x0b = n0;  x1b = n1;
    }

    // In-wave butterfly: every lane ends with the full z for both samples.
    #pragma unroll
    for (int s = 0; s < 2; ++s)
        #pragma unroll
        for (int k = 0; k < NC; ++k) {
            float v = acc[s][k];
            #pragma unroll
            for (int off = 32; off > 0; off >>= 1) v += __shfl_xor(v, off, 64);
            acc[s][k] = v;
        }

    // Phase 3: G = W^T W from LDS-resident Wt. Thread owns d-slice
    // [6*tid, 6*tid+6); 55 upper-tri accumulators; 3 float2 chunks per k
    // (lane stride 24 B -> 2-way bank aliasing, free).
    float gp[55];
    #pragma unroll
    for (int c = 0; c < 55; ++c) gp[c] = 0.0f;
    {
        const int d0 = tid * 6;
        #pragma unroll
        for (int j = 0; j < 3; ++j) {
            float rk[NC][2];
            #pragma unroll
            for (int k = 0; k < NC; ++k) {
                const float2 v = *reinterpret_cast<const float2*>(
                    &Wts[k * ND + d0 + 2 * j]);
                rk[k][0] = v.x; rk[k][1] = v.y;
            }
            int c = 0;
            #pragma unroll
            for (int a = 0; a < NC; ++a)
                #pragma unroll
                for (int b = a; b < NC; ++b) {
                    gp[c] = fmaf(rk[a][0], rk[b][0], gp[c]);
                    gp[c] = fmaf(rk[a][1], rk[b][1], gp[c]);
                    ++c;
                }
        }
    }
    #pragma unroll
    for (int c = 0; c < 55; ++c) {
        #pragma unroll
        for (int off = 32; off > 0; off >>= 1) gp[c] += __shfl_xor(gp[c], off, 64);
    }
    if (lane == 0) {
        #pragma unroll
        for (int c = 0; c < 55; ++c) gpart[wv][c] = gp[c];
    }
    __syncthreads();
    if (tid < 55) {
        float g = 0.0f;
        #pragma unroll
        for (int w = 0; w < 8; ++w) g += gpart[w][tid];
        int idx = tid, i = 0;
        while (idx >= (NC - i)) { idx -= (NC - i); ++i; }
        const int j = i + idx;
        Gs[i * NC + j] = g;
        Gs[j * NC + i] = g;
    }
    __syncthreads();

    // Phase 4: analytic epilogue. Lane 0 -> sample s0, lane 1 -> s0+1.
    if (lane < 2) {
        float z[NC];
        #pragma unroll
        for (int k = 0; k < NC; ++k) z[k] = (lane == 0) ? acc[0][k] : acc[1][k];

        float zm = z[0];
        #pragma unroll
        for (int k = 1; k < NC; ++k) zm = fmaxf(zm, z[k]);
        float e[NC], Zs = 0.0f;
        #pragma unroll
        for (int k = 0; k < NC; ++k) { e[k] = expf(z[k] - zm); Zs += e[k]; }
        const float inv = 1.0f / Zs;

        float sg[NC], p[NC], sq[NC], u[NC];
        #pragma unroll
        for (int k = 0; k < NC; ++k) {
            sg[k] = e[k] * inv;                 // softmax probs (sigma)
            p[k]  = kAlpha * sg[k] + kNumStab;  // stabilized probs
            sq[k] = sqrtf(p[k]);                // s
            u[k]  = sg[k] / sq[k];              // sigma / s
        }
        const float q = 1.0f - sq[NM];

        // v = G*sigma, t = sigma^T G sigma
        float v[NC], t = 0.0f;
        #pragma unroll
        for (int k = 0; k < NC; ++k) {
            float a = 0.0f;
            #pragma unroll
            for (int j = 0; j < NC; ++j) a = fmaf(Gs[k * NC + j], sg[j], a);
            v[k] = a;
            t = fmaf(sg[k], a, t);
        }
        const float vM = v[NM], uM = u[NM];
        const float QMM = Gs[NC * NC - 1] - 2.0f * vM + t;

        float sumJ = 0.0f;
        #pragma unroll
        for (int i = 0; i < NM; ++i) {
            const float Qii = Gs[i * NC + i] - 2.0f * v[i] + t;
            const float QiM = Gs[i * NC + NM] - v[i] - vM + t;
            const float r = sq[i] / q;
            sumJ += u[i] * u[i] * Qii
                  + 2.0f * u[i] * uM * r * QiM
                  + uM * uM * r * r * QMM;
        }
        const float jn = (kAlpha / q) * sqrtf(fmaxf(sumJ, 0.0f));

        float ssum = 0.0f;
        #pragma unroll
        for (int k = 0; k < NC; ++k) ssum += sq[k];
        const float ac = fminf(1.0f, fmaxf(-1.0f, ssum * kInvSqrtC));
        const float delta = 2.0f * acosf(ac);

        float psum = 0.0f;
        #pragma unroll
        for (int k = 0; k < NM; ++k) psum += p[k];
        const float rho = (2.0f * q - psum) / q;

        const float a = jn - delta / (rho * kEps);
        regs[wv * 2 + lane] = (a > 0.0f) ? a : expm1f(a);
    }
    __syncthreads();
    if (tid == 0) {
        float bs = 0.0f;
        #pragma unroll
        for (int i = 0; i < 16; ++i) bs += regs[i];
        atomicAdd(out, bs * (1.0f / (float)NB));
    }
}

extern "C" void kernel_launch(void* const* d_in, const int* in_sizes, int n_in,
                              void* d_out, int out_size, void* d_ws, size_t ws_size,
                              hipStream_t stream) {
    const float* data = (const float*)d_in[0];
    const float* W    = (const float*)d_in[1];
    float* out = (float*)d_out;

    // d_out is re-poisoned to 0xAA before every timed replay -> zero the
    // single accumulator (4-byte fill; cheap, off the HBM critical path).
    hipMemsetAsync(out, 0, sizeof(float), stream);
    jacreg_fused_kernel<<<NB / 16, 512, 0, stream>>>(data, W, out);
}